// Round 5
// baseline (342.643 us; speedup 1.0000x reference)
//
#include <hip/hip_runtime.h>

constexpr int K_CODES = 512;
constexpr int D_DIM   = 64;
constexpr int HW      = 4096;               // 64*64
constexpr int BATCH   = 32;
constexpr int N_ROWS  = BATCH * HW;         // 131072
constexpr int HALF    = BATCH * D_DIM * HW; // elements per output tensor
constexpr int RPB     = 64;                 // rows per block (one per lane)
constexpr int KPW     = 128;                // codes per wave (512 / 4 waves)

// ee[k] = |e_k|^2: sequential d, separate mul/add rounding (matches f32 reference)
__global__ void ee_precompute(const float* __restrict__ emb, float* __restrict__ ee) {
#pragma clang fp contract(off)
    int k = blockIdx.x * blockDim.x + threadIdx.x;
    if (k < K_CODES) {
        const float* w = emb + k * D_DIM;
        float acc = 0.f;
        for (int d = 0; d < D_DIM; ++d) { float q = w[d] * w[d]; acc = acc + q; }
        ee[k] = acc;
    }
}

// 256 threads = 4 waves over 64 rows; lane <-> row, wave <-> 128-code range.
// z lives in LDS (z_lds[d][lane]: 2-lanes/bank = free aliasing), so VGPR
// pressure stays ~30 and the allocator has no reason to remat global loads
// (round-4 failure mode: VGPR=40 proved zr[64] was being reloaded in-loop).
// Codebook + ee via wave-uniform s_load path (readfirstlane, SGPR~112, proven).
// Bit-exact f32 reference emulation (absmax 0.0 in rounds 2-4):
//   dist = fl( fl(zz - fl(2*dot)) + ee ), zz sequential separate-rounded,
//   dot sequential fma chain, argmin first-occurrence (strict <, ascending k).
__global__ __launch_bounds__(256, 8) void vq_nearest(const float* __restrict__ zin,
                                                     const float* __restrict__ emb,
                                                     const float* __restrict__ ee,
                                                     float* __restrict__ out) {
#pragma clang fp contract(off)
    __shared__ float z_lds[D_DIM][RPB];     // [d][row-lane], 16 KB
    __shared__ float s_best[4][RPB];
    __shared__ int   s_bidx[4][RPB];

    const int tid  = threadIdx.x;
    const int wave = tid >> 6;
    const int lane = tid & 63;

    const int row = blockIdx.x * RPB + lane;
    const int b   = row >> 12;
    const int p   = row & (HW - 1);
    const float* zp = zin + (size_t)b * (D_DIM * HW) + p;

    // cooperative stage: wave w loads d in [16w,16w+16) for all 64 rows.
    // global: consecutive lanes -> consecutive p -> coalesced.
    // lds write: fixed d, lane-stride-1 -> conflict-free.
#pragma unroll
    for (int dd = 0; dd < 16; ++dd) {
        const int d = wave * 16 + dd;
        z_lds[d][lane] = zp[(size_t)d * HW];
    }
    __syncthreads();

    // zz: strict sequential sum of squares, separate rounding (from LDS)
    float zz = 0.f;
#pragma unroll
    for (int d = 0; d < D_DIM; ++d) {
        const float zv = z_lds[d][lane];
        const float q  = zv * zv;
        zz = zz + q;
    }

    // wave-uniform code range, forced into an SGPR
    const int kbase = __builtin_amdgcn_readfirstlane(wave) * KPW;
    const float* wbase  = emb + (size_t)kbase * D_DIM;  // uniform -> s_load
    const float* eebase = ee + kbase;                   // uniform -> s_load

    float best = 3.4e38f;
    int   bi   = kbase;

    for (int k0 = 0; k0 < KPW; k0 += 8) {
        const float* w = wbase + (size_t)k0 * D_DIM;
        float dot[8];
#pragma unroll
        for (int j = 0; j < 8; ++j) dot[j] = 0.f;
#pragma unroll
        for (int d = 0; d < D_DIM; ++d) {
            const float z = z_lds[d][lane];             // ds_read, 8-way reuse
#pragma unroll
            for (int j = 0; j < 8; ++j)
                dot[j] = __builtin_fmaf(w[j * D_DIM + d], z, dot[j]);
        }
#pragma unroll
        for (int j = 0; j < 8; ++j) {
            const float m    = 2.0f * dot[j];        // exact
            const float s    = zz - m;               // one rounding
            const float dist = s + eebase[k0 + j];   // one rounding
            if (dist < best) { best = dist; bi = kbase + k0 + j; }
        }
    }

    s_best[wave][lane] = best;
    s_bidx[wave][lane] = bi;
    __syncthreads();

    // cross-wave argmin; wave order ascending in k, strict < keeps
    // first-occurrence semantics exact
    float b0 = s_best[0][lane];
    int   i0 = s_bidx[0][lane];
#pragma unroll
    for (int w2 = 1; w2 < 4; ++w2) {
        const float bw = s_best[w2][lane];
        if (bw < b0) { b0 = bw; i0 = s_bidx[w2][lane]; }
    }

    // gather + write both outputs; wave w covers d in [16w, 16w+16)
    const float* wb = emb + (size_t)i0 * D_DIM;
    float* o1 = out + (size_t)b * (D_DIM * HW) + p;
    float* o2 = o1 + HALF;
#pragma unroll
    for (int dd = 0; dd < 16; ++dd) {
        const int d = wave * 16 + dd;
        const float v = wb[d];
        o1[(size_t)d * HW] = v;
        o2[(size_t)d * HW] = v;
    }
}

extern "C" void kernel_launch(void* const* d_in, const int* in_sizes, int n_in,
                              void* d_out, int out_size, void* d_ws, size_t ws_size,
                              hipStream_t stream) {
    const float* z   = (const float*)d_in[0];
    const float* emb = (const float*)d_in[1];
    float* ee  = (float*)d_ws;
    float* out = (float*)d_out;
    hipLaunchKernelGGL(ee_precompute, dim3(2), dim3(256), 0, stream, emb, ee);
    hipLaunchKernelGGL(vq_nearest, dim3(N_ROWS / RPB), dim3(256), 0, stream,
                       z, emb, ee, out);
}